// Round 4
// baseline (136.166 us; speedup 1.0000x reference)
//
#include <hip/hip_runtime.h>
#include <hip/hip_cooperative_groups.h>
#include <cstdint>
#include <cstddef>

#define BB   32
#define AA   3
#define FF   76
#define NCH  85
#define NL   50
#define NCLS 80
#define CELLS (AA*FF*FF)                         /* 17328 */
#define CPB  256
#define CPT  4
#define CELLS_PB (CPB*CPT)                       /* 1024 */
#define BPB  ((CELLS + CELLS_PB - 1)/CELLS_PB)   /* 17 */
#define GRID (BB*BPB)                            /* 544 */

namespace cg = cooperative_groups;

__device__ __forceinline__ float slog(float x) {
    // torch-BCELoss-style clamped log
    return fmaxf(logf(fmaxf(x, 1e-43f)), -100.0f);
}

// ---------------- single cooperative kernel ----------------
__global__ void __launch_bounds__(CPB) k_all(const float* __restrict__ outp,
                                             const float* __restrict__ pred,
                                             const float* __restrict__ labels,
                                             float* __restrict__ partial,
                                             float* __restrict__ out) {
    __shared__ float4 Sbox[NL];        // truth {l, r, bot, top}
    __shared__ float2 Sak[NL];         // {area, key_bits}
    __shared__ float  Srec[NL][6];     // {fx, fy, lw, lh, sc, cls_bits}
    __shared__ int    Smx;
    __shared__ float  red[CPB];

    int bid  = blockIdx.x;
    int b    = bid / BPB;
    int blk  = bid % BPB;
    int base = blk * CELLS_PB + (int)threadIdx.x;

    // issue all big-latency loads up front (4x MLP), consumed after record phase
    int    cell[CPT];
    bool   live[CPT];
    size_t ci[CPT];
    float4 pb[CPT];
    float  p4[CPT];
    #pragma unroll
    for (int c = 0; c < CPT; ++c) {
        cell[c] = base + c * CPB;                  // coalesced across the wave
        live[c] = cell[c] < CELLS;
        ci[c]   = (size_t)b * CELLS + (size_t)(live[c] ? cell[c] : 0);
        pb[c]   = ((const float4*)pred)[ci[c]];
        p4[c]   = outp[ci[c] * NCH + 4];
    }

    // ---- wave 0: build this batch's label records in LDS ----
    if (threadIdx.x < 64) {
        int  n   = (int)threadIdx.x;
        bool has = n < NL;
        bool valid = false;
        if (has) {
            const float* L = labels + ((size_t)b * NL + n) * 5;
            float c0 = L[0], x = L[1], y = L[2], w = L[3], h = L[4];
            valid = (c0 + x + y + w + h) > 0.0f;
            float vf = valid ? 1.0f : 0.0f;

            float tx = x * 0.125f, ty = y * 0.125f;
            float tw = w * 0.125f, th = h * 0.125f;
            int   ti = (int)tx, tj = (int)ty;
            float twm = tw * vf, thm = th * vf;

            const float ag[9][2] = {   // ANCHORS / 8, exact in fp32
                {1.5f, 2.0f}, {2.375f, 4.5f}, {5.0f, 3.5f},
                {4.5f, 9.375f}, {9.5f, 6.875f}, {9.0f, 18.25f},
                {17.75f, 13.75f}, {24.0f, 30.375f}, {57.375f, 50.125f}
            };
            float at = twm * thm;
            float best = -1.0f; int bi = 0;
            #pragma unroll
            for (int k = 0; k < 9; ++k) {
                float iw = fminf(twm, ag[k][0]);
                float ih = fminf(thm, ag[k][1]);
                float inter = (iw > 0.0f && ih > 0.0f) ? iw * ih : 0.0f;
                float iou = inter / (at + ag[k][0] * ag[k][1] - inter);
                if (iou > best) { best = iou; bi = k; }   // first-max wins (jnp.argmax)
            }
            int  bn    = bi % 3;
            bool write = (bi < 3) && valid;
            int  key   = write ? (bn * FF * FF + tj * FF + ti) : -1;

            float tbx = tx * vf, tby = ty * vf;
            Sbox[n] = make_float4(tbx - twm * 0.5f, tbx + twm * 0.5f,
                                  tby - thm * 0.5f, tby + thm * 0.5f);
            Sak[n]  = make_float2(twm * thm, __int_as_float(key));
            Srec[n][0] = tx - (float)ti;
            Srec[n][1] = ty - (float)tj;
            Srec[n][2] = logf(tw / ag[bn][0] + 1e-16f);
            Srec[n][3] = logf(th / ag[bn][1] + 1e-16f);
            Srec[n][4] = sqrtf(2.0f - tw * th * (1.0f / (float)(FF * FF)));
            Srec[n][5] = __int_as_float((int)c0);
        }
        unsigned long long mb = __ballot(has && valid);
        if (threadIdx.x == 0) Smx = mb ? (64 - __builtin_clzll(mb)) : 0;
    }
    __syncthreads();

    int mx = Smx;

    float plx[CPT], prx[CPT], ply[CPT], pry[CPT], ap[CPT], bestiou[CPT];
    int   mn[CPT];
    #pragma unroll
    for (int c = 0; c < CPT; ++c) {
        plx[c] = pb[c].x - pb[c].z * 0.5f;  prx[c] = pb[c].x + pb[c].z * 0.5f;
        ply[c] = pb[c].y - pb[c].w * 0.5f;  pry[c] = pb[c].y + pb[c].w * 0.5f;
        ap[c]  = pb[c].z * pb[c].w;
        bestiou[c] = 0.0f;  mn[c] = -1;
    }

    // one LDS broadcast pair serves all 4 cells
    for (int n = 0; n < mx; ++n) {
        float4 tb  = Sbox[n];                       // ds_read_b128, broadcast
        float2 ak  = Sak[n];                        // ds_read_b64,  broadcast
        int    key = __float_as_int(ak.y);
        #pragma unroll
        for (int c = 0; c < CPT; ++c) {
            float lx = fmaxf(plx[c], tb.x);
            float rx = fminf(prx[c], tb.y);
            float ly = fmaxf(ply[c], tb.z);
            float ry = fminf(pry[c], tb.w);
            float w = rx - lx, h = ry - ly;
            float inter = (fminf(w, h) > 0.0f) ? w * h : 0.0f;
            bestiou[c] = fmaxf(bestiou[c], inter * __builtin_amdgcn_rcpf(ap[c] + ak.x - inter));
            if (key == cell[c]) mn[c] = n;          // last write wins
        }
    }

    float loss = 0.0f;
    #pragma unroll
    for (int c = 0; c < CPT; ++c) {
        if (!live[c]) continue;
        if (mn[c] >= 0) {
            const float* op = outp + ci[c] * NCH;
            const float* r  = Srec[mn[c]];
            loss += -slog(p4[c]);                   // obj, t=1
            float s = r[4], s2 = s * s;
            float t0 = r[0], t1 = r[1];
            float p0 = op[0], p1 = op[1];
            loss += -s2 * (t0 * slog(p0) + (1.0f - t0) * slog(1.0f - p0));
            loss += -s2 * (t1 * slog(p1) + (1.0f - t1) * slog(1.0f - p1));
            float d0 = (op[2] - r[2]) * s;
            float d1 = (op[3] - r[3]) * s;
            loss += 0.5f * (d0 * d0 + d1 * d1);
            // class BCE, branch-free: sum -slog(1-p) over all, fix up true class
            int   cls = __float_as_int(r[5]);
            float cl  = 0.0f;
            #pragma unroll 8
            for (int k = 0; k < NCLS; ++k) cl += slog(1.0f - op[5 + k]);
            float pc = op[5 + cls];
            loss += -cl + slog(1.0f - pc) - slog(pc);
        } else if (!(bestiou[c] > 0.7f)) {
            loss += -slog(1.0f - p4[c]);            // obj, t=0, not ignored
        }
    }

    // block tree-reduce (deterministic)
    red[threadIdx.x] = loss;
    __syncthreads();
    for (int s = CPB / 2; s > 0; s >>= 1) {
        if ((int)threadIdx.x < s) red[threadIdx.x] += red[threadIdx.x + s];
        __syncthreads();
    }
    if (threadIdx.x == 0) partial[bid] = red[0];
    __threadfence();                                // device-scope release of partial[bid]

    cg::this_grid().sync();                         // grid-wide barrier + memory ordering

    if (bid == 0) {
        float s = 0.0f;
        for (int i = threadIdx.x; i < GRID; i += CPB) s += partial[i];
        red[threadIdx.x] = s;
        __syncthreads();
        for (int k = 128; k > 0; k >>= 1) {
            if ((int)threadIdx.x < k) red[threadIdx.x] += red[threadIdx.x + k];
            __syncthreads();
        }
        if (threadIdx.x == 0) out[0] = red[0];
    }
}

extern "C" void kernel_launch(void* const* d_in, const int* in_sizes, int n_in,
                              void* d_out, int out_size, void* d_ws, size_t ws_size,
                              hipStream_t stream) {
    const float* outp   = (const float*)d_in[0];  // [32,3,76,76,85] probabilities
    const float* pred   = (const float*)d_in[1];  // [32,3,76,76,4] decoded boxes
    const float* labels = (const float*)d_in[2];  // [32,50,5]
    float*       partial = (float*)d_ws;          // 544 floats, fully overwritten each call
    float*       out     = (float*)d_out;

    void* args[] = { (void*)&outp, (void*)&pred, (void*)&labels, (void*)&partial, (void*)&out };
    hipLaunchCooperativeKernel((const void*)k_all, dim3(GRID), dim3(CPB), args, 0, stream);
}

// Round 5
// 31.682 us; speedup vs baseline: 4.2979x; 4.2979x over previous
//
#include <hip/hip_runtime.h>
#include <cstdint>
#include <cstddef>

#define BB   32
#define AA   3
#define FF   76
#define NCH  85
#define NL   50
#define NCLS 80
#define CELLS (AA*FF*FF)                         /* 17328 */
#define CPB  256
#define CPT  2
#define CELLS_PB (CPB*CPT)                       /* 512 */
#define BPB  ((CELLS + CELLS_PB - 1)/CELLS_PB)   /* 34 */
#define GRID (BB*BPB)                            /* 1088 */

__device__ __forceinline__ float slog(float x) {
    // torch-BCELoss-style clamped log
    return fmaxf(logf(fmaxf(x, 1e-43f)), -100.0f);
}

// ---------------- main kernel: records in-block + per-cell loss ----------------
__global__ void __launch_bounds__(CPB) k_main(const float* __restrict__ outp,
                                              const float* __restrict__ pred,
                                              const float* __restrict__ labels,
                                              float* __restrict__ partial) {
    __shared__ float4 Sbox[NL];          // truth {l, r, bot, top}
    __shared__ float  Saz[NL];           // area * (0.7/1.7)
    __shared__ float  Srec[NL][6];       // {fx, fy, lw, lh, sc, cls_bits}
    __shared__ int    Smatch[CELLS_PB];  // per-cell matched label idx or -1
    __shared__ int    Smx;
    __shared__ float  red[CPB / 64];

    const float C717 = 0.7f / 1.7f;

    int bid  = blockIdx.x;
    int b    = bid / BPB;
    int blk  = bid % BPB;
    int base = blk * CELLS_PB;

    // issue the big-latency loads up front; consumed after the record phase
    int    cell0 = base + (int)threadIdx.x;
    int    cell1 = cell0 + CPB;
    bool   live0 = cell0 < CELLS;
    bool   live1 = cell1 < CELLS;
    size_t ci0   = (size_t)b * CELLS + (size_t)(live0 ? cell0 : 0);
    size_t ci1   = (size_t)b * CELLS + (size_t)(live1 ? cell1 : 0);
    float4 pb0   = ((const float4*)pred)[ci0];
    float4 pb1   = ((const float4*)pred)[ci1];
    float  p40   = outp[ci0 * NCH + 4];
    float  p41   = outp[ci1 * NCH + 4];

    // init match table, then barrier before wave 0 scatters into it
    Smatch[threadIdx.x]       = -1;
    Smatch[threadIdx.x + CPB] = -1;
    __syncthreads();

    // ---- wave 0: build this batch's label records in LDS ----
    if (threadIdx.x < 64) {
        int  n   = (int)threadIdx.x;
        bool has = n < NL;
        bool valid = false;
        if (has) {
            const float* L = labels + ((size_t)b * NL + n) * 5;
            float c0 = L[0], x = L[1], y = L[2], w = L[3], h = L[4];
            valid = (c0 + x + y + w + h) > 0.0f;
            float vf = valid ? 1.0f : 0.0f;

            float tx = x * 0.125f, ty = y * 0.125f;
            float tw = w * 0.125f, th = h * 0.125f;
            int   ti = (int)tx, tj = (int)ty;
            float twm = tw * vf, thm = th * vf;

            const float ag[9][2] = {   // ANCHORS / 8, exact in fp32
                {1.5f, 2.0f}, {2.375f, 4.5f}, {5.0f, 3.5f},
                {4.5f, 9.375f}, {9.5f, 6.875f}, {9.0f, 18.25f},
                {17.75f, 13.75f}, {24.0f, 30.375f}, {57.375f, 50.125f}
            };
            float at = twm * thm;
            float best = -1.0f; int bi = 0;
            #pragma unroll
            for (int k = 0; k < 9; ++k) {
                float iw = fminf(twm, ag[k][0]);
                float ih = fminf(thm, ag[k][1]);
                float inter = (iw > 0.0f && ih > 0.0f) ? iw * ih : 0.0f;
                float iou = inter / (at + ag[k][0] * ag[k][1] - inter);
                if (iou > best) { best = iou; bi = k; }   // first-max wins (jnp.argmax)
            }
            int  bn    = bi % 3;
            bool write = (bi < 3) && valid;

            float tbx = tx * vf, tby = ty * vf;
            Sbox[n] = make_float4(tbx - twm * 0.5f, tbx + twm * 0.5f,
                                  tby - thm * 0.5f, tby + thm * 0.5f);
            Saz[n]  = twm * thm * C717;
            Srec[n][0] = tx - (float)ti;
            Srec[n][1] = ty - (float)tj;
            Srec[n][2] = logf(tw / ag[bn][0] + 1e-16f);
            Srec[n][3] = logf(th / ag[bn][1] + 1e-16f);
            Srec[n][4] = sqrtf(2.0f - tw * th * (1.0f / (float)(FF * FF)));
            Srec[n][5] = __int_as_float((int)c0);

            if (write) {
                int key = bn * FF * FF + tj * FF + ti;
                int rel = key - base;
                if (rel >= 0 && rel < CELLS_PB)
                    atomicMax(&Smatch[rel], n);           // max n == last write wins
            }
        }
        unsigned long long mb = __ballot(has && valid);
        if (threadIdx.x == 0) Smx = mb ? (64 - __builtin_clzll(mb)) : 0;
    }
    __syncthreads();

    int mx  = Smx;
    int mn0 = Smatch[threadIdx.x];
    int mn1 = Smatch[threadIdx.x + CPB];

    float plx0 = pb0.x - pb0.z * 0.5f, prx0 = pb0.x + pb0.z * 0.5f;
    float ply0 = pb0.y - pb0.w * 0.5f, pry0 = pb0.y + pb0.w * 0.5f;
    float apz0 = pb0.z * pb0.w * C717;
    float plx1 = pb1.x - pb1.z * 0.5f, prx1 = pb1.x + pb1.z * 0.5f;
    float ply1 = pb1.y - pb1.w * 0.5f, pry1 = pb1.y + pb1.w * 0.5f;
    float apz1 = pb1.z * pb1.w * C717;

    float md0 = -1.0f, md1 = -1.0f;      // max(inter - thr); >0 => ignored
    for (int n = 0; n < mx; ++n) {
        float4 tb = Sbox[n];             // ds_read_b128, broadcast
        float  az = Saz[n];              // ds_read_b32,  broadcast

        float lx0 = fmaxf(plx0, tb.x), rx0 = fminf(prx0, tb.y);
        float ly0 = fmaxf(ply0, tb.z), ry0 = fminf(pry0, tb.w);
        float w0 = fmaxf(rx0 - lx0, 0.0f), h0 = fmaxf(ry0 - ly0, 0.0f);
        md0 = fmaxf(md0, w0 * h0 - (apz0 + az));

        float lx1 = fmaxf(plx1, tb.x), rx1 = fminf(prx1, tb.y);
        float ly1 = fmaxf(ply1, tb.z), ry1 = fminf(pry1, tb.w);
        float w1 = fmaxf(rx1 - lx1, 0.0f), h1 = fmaxf(ry1 - ly1, 0.0f);
        md1 = fmaxf(md1, w1 * h1 - (apz1 + az));
    }

    float loss = 0.0f;
    #pragma unroll
    for (int c = 0; c < CPT; ++c) {
        bool   live = c ? live1 : live0;
        int    mn   = c ? mn1   : mn0;
        float  p4   = c ? p41   : p40;
        float  md   = c ? md1   : md0;
        size_t ci   = c ? ci1   : ci0;
        if (!live) continue;
        if (mn >= 0) {
            const float* op = outp + ci * NCH;
            const float* r  = Srec[mn];
            loss += -slog(p4);                          // obj, t=1
            float s = r[4], s2 = s * s;
            float t0 = r[0], t1 = r[1];
            float p0 = op[0], p1 = op[1];
            loss += -s2 * (t0 * slog(p0) + (1.0f - t0) * slog(1.0f - p0));
            loss += -s2 * (t1 * slog(p1) + (1.0f - t1) * slog(1.0f - p1));
            float d0 = (op[2] - r[2]) * s;
            float d1 = (op[3] - r[3]) * s;
            loss += 0.5f * (d0 * d0 + d1 * d1);
            // class BCE, branch-free: sum -slog(1-p) over all, fix up true class
            int   cls = __float_as_int(r[5]);
            float cl  = 0.0f;
            #pragma unroll 8
            for (int k = 0; k < NCLS; ++k) cl += slog(1.0f - op[5 + k]);
            float pc = op[5 + cls];
            loss += -cl + slog(1.0f - pc) - slog(pc);
        } else if (!(md > 0.0f)) {
            loss += -slog(1.0f - p4);                   // obj, t=0, not ignored
        }
    }

    // wave shuffle-reduce, then tiny cross-wave reduce
    #pragma unroll
    for (int off = 32; off > 0; off >>= 1) loss += __shfl_down(loss, off);
    if ((threadIdx.x & 63) == 0) red[threadIdx.x >> 6] = loss;
    __syncthreads();
    if (threadIdx.x == 0)
        partial[bid] = red[0] + red[1] + red[2] + red[3];
}

// ---------------- deterministic final reduce ----------------
__global__ void k_reduce(const float* __restrict__ partial, float* __restrict__ out) {
    __shared__ float red[256];
    float s = 0.0f;
    for (int i = threadIdx.x; i < GRID; i += 256) s += partial[i];
    red[threadIdx.x] = s;
    __syncthreads();
    for (int k = 128; k > 0; k >>= 1) {
        if ((int)threadIdx.x < k) red[threadIdx.x] += red[threadIdx.x + k];
        __syncthreads();
    }
    if (threadIdx.x == 0) out[0] = red[0];
}

extern "C" void kernel_launch(void* const* d_in, const int* in_sizes, int n_in,
                              void* d_out, int out_size, void* d_ws, size_t ws_size,
                              hipStream_t stream) {
    const float* outp   = (const float*)d_in[0];  // [32,3,76,76,85] probabilities
    const float* pred   = (const float*)d_in[1];  // [32,3,76,76,4] decoded boxes
    const float* labels = (const float*)d_in[2];  // [32,50,5]

    float* partial = (float*)d_ws;                // 1088 floats, fully overwritten each call

    k_main<<<GRID, CPB, 0, stream>>>(outp, pred, labels, partial);
    k_reduce<<<1, 256, 0, stream>>>(partial, (float*)d_out);
}